// Round 7
// baseline (36.265 us; speedup 1.0000x reference)
//
#include <hip/hip_runtime.h>
#include <math.h>

#define K_TOP 16
#define D_DIM 1024
#define N_ROWS 2048                       // 32 * 64 rows

typedef float f32x4 __attribute__((ext_vector_type(4)));

// One block (256 thr) per row q. All 4 waves zero 4 k-rows each (16 x 1KB
// contiguous f32x4 stores per wave, issued from cycle ~0). Wave 0 issues its
// input loads BEFORE its zero stores, then runs the 16-round butterfly
// argmax + rank sort on the in-flight data while stores drain. After the
// barrier, wave 0 lanes 0..15 scatter the 16 ones into L2-dirty lines.
// No LDS; selection state lives entirely in wave-0 registers.
__global__ __launch_bounds__(256) void dps_topk_kernel(
    const float* __restrict__ logits,  // (64, 1024)
    const float* __restrict__ gn,      // (32, 64, 1024)
    float* __restrict__ out)           // (32, 64, 16, 1024)
{
    const int tid  = threadIdx.x;
    const int lane = tid & 63;
    const int wave = tid >> 6;
    const int q    = blockIdx.x;
    const int r    = q & 63;

    float* orow = out + (size_t)q * (K_TOP * D_DIM);
    f32x4* o4   = reinterpret_cast<f32x4*>(orow);
    const f32x4 z = {0.f, 0.f, 0.f, 0.f};

    int my_sel = 0, rank = 0;

    if (wave != 0) {
        // Zero k-rows (wave-1)*4 .. (wave-1)*4+3 : 16 x 1KB stores.
        f32x4* base = o4 + (wave - 1) * 1024 + lane;
        #pragma unroll
        for (int i = 0; i < 16; ++i) base[i * 64] = z;
    } else {
        // ---- issue input loads first (lane owns 16 consecutive floats) ----
        const f32x4* l4 = reinterpret_cast<const f32x4*>(
            logits + (size_t)r * D_DIM + lane * 16);
        const f32x4* g4 = reinterpret_cast<const f32x4*>(
            gn + (size_t)q * D_DIM + lane * 16);
        f32x4 a0 = l4[0], a1 = l4[1], a2 = l4[2], a3 = l4[3];
        f32x4 b0 = g4[0], b1 = g4[1], b2 = g4[2], b3 = g4[3];

        // ---- then issue zero stores for k-rows 12..15 (fire-and-forget) ----
        f32x4* base = o4 + 3 * 1024 + lane;
        #pragma unroll
        for (int i = 0; i < 16; ++i) base[i * 64] = z;

        // ---- compute perturbed values (waits only on the loads) ----
        float v[16];
        v[0]=a0.x+b0.x;  v[1]=a0.y+b0.y;  v[2]=a0.z+b0.z;  v[3]=a0.w+b0.w;
        v[4]=a1.x+b1.x;  v[5]=a1.y+b1.y;  v[6]=a1.z+b1.z;  v[7]=a1.w+b1.w;
        v[8]=a2.x+b2.x;  v[9]=a2.y+b2.y;  v[10]=a2.z+b2.z; v[11]=a2.w+b2.w;
        v[12]=a3.x+b3.x; v[13]=a3.y+b3.y; v[14]=a3.z+b3.z; v[15]=a3.w+b3.w;

        // ---- 16 rounds of wave-wide argmax ----
        unsigned chosen = 0;   // bitmask of already-taken j's in THIS lane
        for (int round = 0; round < K_TOP; ++round) {
            float bv = -INFINITY;
            int   bi = 0x7fffffff;
            #pragma unroll
            for (int j = 0; j < 16; ++j) {
                if (!(chosen & (1u << j))) {
                    // strict > keeps smaller j (=smaller index) on ties
                    if (v[j] > bv) { bv = v[j]; bi = lane * 16 + j; }
                }
            }
            #pragma unroll
            for (int off = 32; off > 0; off >>= 1) {
                const float ov = __shfl_xor(bv, off);
                const int   oi = __shfl_xor(bi, off);
                if (ov > bv || (ov == bv && oi < bi)) { bv = ov; bi = oi; }
            }
            if (lane == (bi >> 4)) chosen |= 1u << (bi & 15);
            if (lane == round)     my_sel = bi;
        }

        // ---- rank among the 16 winners = ascending index order ----
        #pragma unroll
        for (int j = 0; j < K_TOP; ++j) {
            const int other = __shfl(my_sel, j);
            rank += (other < my_sel) ? 1 : 0;
        }
    }

    __syncthreads();   // all zeros of this row's block landed

    // ---- scatter the 16 ones: out[q][rank][my_sel] = 1 ----
    if (wave == 0 && lane < K_TOP) {
        orow[rank * D_DIM + my_sel] = 1.0f;
    }
}

extern "C" void kernel_launch(void* const* d_in, const int* in_sizes, int n_in,
                              void* d_out, int out_size, void* d_ws, size_t ws_size,
                              hipStream_t stream) {
    const float* logits = (const float*)d_in[0];  // (64, 1024) f32
    const float* gn     = (const float*)d_in[1];  // (32, 64, 1024) f32
    float* out          = (float*)d_out;          // (32, 64, 16, 1024) f32

    dps_topk_kernel<<<dim3(N_ROWS), dim3(256), 0, stream>>>(logits, gn, out);
}